// Round 13
// baseline (333.289 us; speedup 1.0000x reference)
//
#include <hip/hip_runtime.h>
#include <math.h>

#define D_MODEL 1024
#define D_HIDDEN 4096
#define NUM_HEADS 16
#define D_K 64
#define EPS 1e-6f
#define MASK_FILL -1e9f
#define BATCH 2
#define SEQ 2048
#define ROWS (BATCH * SEQ)   // 4096

typedef unsigned short ushort_t;
typedef __attribute__((ext_vector_type(8))) short bf16x8;
typedef __attribute__((ext_vector_type(4))) float f32x4;

__device__ __forceinline__ unsigned short f2bf(float f) {
    union { float f; unsigned int u; } v; v.f = f;
    unsigned int r = v.u + 0x7fffu + ((v.u >> 16) & 1u);   // RNE
    return (unsigned short)(r >> 16);
}
__device__ __forceinline__ float bf2f(unsigned short u) {
    union { unsigned int u; float f; } v; v.u = ((unsigned int)u) << 16;
    return v.f;
}

__device__ __forceinline__ void load_lds16(const void* g, void* l) {
    __builtin_amdgcn_global_load_lds(
        (__attribute__((address_space(1))) void*)g,
        (__attribute__((address_space(3))) void*)l,
        16, 0, 0);
}

// ---------------- LayerNorm ----------------
__global__ __launch_bounds__(256) void ln_kernel(const float* __restrict__ x,
                                                 const float* __restrict__ a,
                                                 const float* __restrict__ b,
                                                 ushort_t* __restrict__ out) {
    int row = blockIdx.x;
    int t = threadIdx.x;
    const float* xr = x + (size_t)row * D_MODEL;

    float4 v = ((const float4*)xr)[t];
    float s  = v.x + v.y + v.z + v.w;
    float ss = v.x*v.x + v.y*v.y + v.z*v.z + v.w*v.w;
    #pragma unroll
    for (int o = 32; o > 0; o >>= 1) {
        s  += __shfl_down(s,  o);
        ss += __shfl_down(ss, o);
    }
    __shared__ float ws0[4], ws1[4];
    __shared__ float mean_s, inv_s;
    int wid = t >> 6, lane = t & 63;
    if (lane == 0) { ws0[wid] = s; ws1[wid] = ss; }
    __syncthreads();
    if (t == 0) {
        float S1 = ws0[0] + ws0[1] + ws0[2] + ws0[3];
        float S2 = ws1[0] + ws1[1] + ws1[2] + ws1[3];
        float mean = S1 / (float)D_MODEL;
        float var  = (S2 - mean * S1) / (float)(D_MODEL - 1);  // Bessel
        mean_s = mean;
        inv_s  = 1.0f / (sqrtf(var) + EPS);
    }
    __syncthreads();
    float mean = mean_s, inv = inv_s;
    float4 av = ((const float4*)a)[t];
    float4 bv = ((const float4*)b)[t];
    ushort4 o;
    o.x = f2bf(av.x * (v.x - mean) * inv + bv.x);
    o.y = f2bf(av.y * (v.y - mean) * inv + bv.y);
    o.z = f2bf(av.z * (v.z - mean) * inv + bv.z);
    o.w = f2bf(av.w * (v.w - mean) * inv + bv.w);
    *(ushort4*)&out[(size_t)row * D_MODEL + (t << 2)] = o;
}

// ---------------- weight transpose fp32->bf16: W[K][N] -> Wt[N][K] ----------------
__device__ __forceinline__ void transpose_tile(const float* W, ushort_t* Wt,
                                               int K, int N, int n0, int k0) {
    __shared__ float tile[64][65];
    int t = threadIdx.x;
    int c4 = t & 15, r = t >> 4;
    #pragma unroll
    for (int p = 0; p < 4; p++) {
        int row = r + 16 * p;
        float4 v = *(const float4*)&W[(size_t)(k0 + row) * N + n0 + 4 * c4];
        tile[row][4*c4+0] = v.x; tile[row][4*c4+1] = v.y;
        tile[row][4*c4+2] = v.z; tile[row][4*c4+3] = v.w;
    }
    __syncthreads();
    #pragma unroll
    for (int p = 0; p < 4; p++) {
        int n = r + 16 * p;
        ushort4 o;
        o.x = f2bf(tile[4*c4+0][n]);
        o.y = f2bf(tile[4*c4+1][n]);
        o.z = f2bf(tile[4*c4+2][n]);
        o.w = f2bf(tile[4*c4+3][n]);
        *(ushort4*)&Wt[(size_t)(n0 + n) * K + k0 + 4 * c4] = o;
    }
}

__global__ __launch_bounds__(256) void transpose4_bf16_kernel(const float* s0, const float* s1,
                                                              const float* s2, const float* s3,
                                                              ushort_t* d0, ushort_t* d1,
                                                              ushort_t* d2, ushort_t* d3) {
    const float* S[4] = {s0, s1, s2, s3};
    ushort_t*    D[4] = {d0, d1, d2, d3};
    int z = blockIdx.z;
    transpose_tile(S[z], D[z], D_MODEL, D_MODEL, blockIdx.x * 64, blockIdx.y * 64);
}

__global__ __launch_bounds__(256) void transpose_ffn_kernel(const float* w1, const float* w2,
                                                            ushort_t* w1t, ushort_t* w2t) {
    int lin = blockIdx.x;
    if (blockIdx.y == 0)
        transpose_tile(w1, w1t, D_MODEL, D_HIDDEN, (lin & 63) * 64, (lin >> 6) * 64);
    else
        transpose_tile(w2, w2t, D_HIDDEN, D_MODEL, (lin & 15) * 64, (lin >> 4) * 64);
}

// ---------------- mask prefix scan ----------------
__global__ __launch_bounds__(256) void mask_scan_kernel(const int* __restrict__ mask,
                                                        int* __restrict__ idx,
                                                        int* __restrict__ nun) {
    int b = blockIdx.x, t = threadIdx.x;
    __shared__ int sums[256];
    const int* m = mask + b * SEQ;
    int loc[8], s = 0;
    #pragma unroll
    for (int i = 0; i < 8; i++) { loc[i] = m[t * 8 + i]; s += loc[i]; }
    sums[t] = s;
    __syncthreads();
    for (int off = 1; off < 256; off <<= 1) {
        int v = sums[t];
        if (t >= off) v += sums[t - off];
        __syncthreads();
        sums[t] = v;
        __syncthreads();
    }
    int c = (t > 0) ? sums[t - 1] : 0;
    #pragma unroll
    for (int i = 0; i < 8; i++)
        if (loc[i]) { idx[b * SEQ + c] = t * 8 + i; c++; }
    if (t == 255) nun[b] = sums[255];
}

// ======== BK=64 staging/read pattern (fattn-style, 128B LDS rows, XOR swizzle) =====
// Stage: wave stages 32 rows per tile; lane l -> row sub l>>3, global chunk (l&7)^(l>>3).
// Read: row r chunk c lives at LDS chunk c ^ (r&7)  -> conflict-free.

// ---------------- unified QKV GEMM, K/V rows gathered in-place via idx ----------------
// R11 (verified): hgather folded into A addressing; per-thread row pointers hoisted to
// the prologue; tail rows clamp to idx[nun-1] (P contribution exp2(-1000)=0 exactly).
// Single-buffered by design: 32 KiB LDS -> 4-5 blocks/CU; inter-block wave overlap hides
// the staging stall (R9 lesson: explicit dbuf here costs occupancy for zero net gain).
__global__ __launch_bounds__(256) void gemm_qkv(const ushort_t* __restrict__ h,
                                                const ushort_t* __restrict__ Wt,   // [3072][1024]
                                                const int* __restrict__ idx,
                                                const int* __restrict__ nunb,
                                                ushort_t* __restrict__ Qout,
                                                ushort_t* __restrict__ K2,
                                                ushort_t* __restrict__ Vt2) {
    __shared__ ushort_t As[128 * 64];
    __shared__ ushort_t Bs[128 * 64];
    const int K = D_MODEL;

    int bx = blockIdx.x, by = blockIdx.y;
    bool isQ = (by < 8);
    int b = bx >> 4;
    int n0 = isQ ? by * 128 : (by - 8) * 128;
    int m0;
    int nun = 0;
    if (isQ) {
        m0 = bx * 128;
    } else {
        nun = nunb[b];
        int mloc = (bx & 15) * 128;
        if (mloc >= ((nun + 127) & ~127)) return;   // block-uniform early exit (pre-barrier)
        m0 = mloc;
    }
    const ushort_t* Bt = Wt + (size_t)(isQ ? 0 : 1024) * K;

    int tid = threadIdx.x;
    int wave = tid >> 6, lane = tid & 63;
    int l8 = lane >> 3, c8 = lane & 7;
    int cg = c8 ^ l8;

    // Per-thread A-row base pointers (4 rows, fixed across K-tiles).
    const ushort_t* gA_c[4];
    #pragma unroll
    for (int c = 0; c < 4; c++) {
        int r = m0 + 32 * wave + l8 + 8 * c;
        int grow;
        if (isQ) {
            grow = r;                                // global row over both batches
        } else {
            int rc = (r < nun) ? r : (nun - 1);      // clamp tail to a valid row
            grow = b * SEQ + idx[b * SEQ + rc];      // gathered unmasked row
        }
        gA_c[c] = h + (size_t)grow * K + cg * 8;
    }
    const ushort_t* gB = Bt + (size_t)(n0 + 32 * wave + l8) * K + cg * 8;
    ushort_t* lA = As + (32 * wave) * 64;
    ushort_t* lB = Bs + (32 * wave) * 64;

    f32x4 acc[4][4];
    #pragma unroll
    for (int i = 0; i < 4; i++)
        #pragma unroll
        for (int j = 0; j < 4; j++) acc[i][j] = (f32x4){0.f, 0.f, 0.f, 0.f};

    int wm = (wave >> 1) * 64, wn = (wave & 1) * 64;
    int fm = lane & 15;
    int fk = (lane >> 4) * 8;
    int swz = (fm & 7) * 8;

    for (int k0 = 0; k0 < K; k0 += 64) {
        __syncthreads();
        #pragma unroll
        for (int c = 0; c < 4; c++) {
            load_lds16(gA_c[c] + k0,                    lA + (8 * c) * 64);
            load_lds16(gB + (size_t)(8 * c) * K + k0,   lB + (8 * c) * 64);
        }
        __syncthreads();

        #pragma unroll
        for (int kh = 0; kh < 2; kh++) {
            int kk = kh * 32;
            bf16x8 af[4], bfr[4];
            #pragma unroll
            for (int i = 0; i < 4; i++)
                af[i] = *(const bf16x8*)&As[(wm + 16 * i + fm) * 64 + ((kk + fk) ^ swz)];
            #pragma unroll
            for (int j = 0; j < 4; j++)
                bfr[j] = *(const bf16x8*)&Bs[(wn + 16 * j + fm) * 64 + ((kk + fk) ^ swz)];
            #pragma unroll
            for (int i = 0; i < 4; i++)
                #pragma unroll
                for (int j = 0; j < 4; j++)
                    acc[i][j] = __builtin_amdgcn_mfma_f32_16x16x32_bf16(af[i], bfr[j], acc[i][j], 0, 0, 0);
        }
    }

    int col_l = lane & 15, row_l = (lane >> 4) * 4;
    #pragma unroll
    for (int i = 0; i < 4; i++) {
        #pragma unroll
        for (int j = 0; j < 4; j++) {
            int col = n0 + wn + 16 * j + col_l;
            int row = m0 + wm + 16 * i + row_l;
            if (isQ) {
                #pragma unroll
                for (int r = 0; r < 4; r++)
                    Qout[(size_t)(row + r) * D_MODEL + col] = f2bf(acc[i][j][r]);
            } else if (col < 1024) {
                ushort_t* K2b = K2 + (size_t)b * SEQ * D_MODEL;
                #pragma unroll
                for (int r = 0; r < 4; r++)
                    K2b[(size_t)(row + r) * D_MODEL + col] = f2bf(acc[i][j][r]);
            } else {
                ushort_t* Vt2b = Vt2 + (size_t)b * D_MODEL * SEQ;
                ushort4 o;
                o.x = f2bf(acc[i][j][0]); o.y = f2bf(acc[i][j][1]);
                o.z = f2bf(acc[i][j][2]); o.w = f2bf(acc[i][j][3]);
                *(ushort4*)&Vt2b[(size_t)(col - 1024) * SEQ + row] = o;
            }
        }
    }
}

// ================= 256x256 8-wave double-buffered pipelined GEMM (VERIFIED R3/R7/R8) ===
// Grid must be >=256 blocks to fill the machine (1 block/CU at 128 KiB LDS) — do NOT use
// for small-N GEMMs (R6 lesson: WO at 64 blocks -> 4.9% occupancy, 3x regression).
// T3+T4: prefetch tile t+1 issued BEFORE waiting tile t; counted s_waitcnt vmcnt(8).
// T5: setprio(1) around MFMA cluster. T2: (row&7) chunk-XOR swizzle (0 bank conflicts).

__device__ __forceinline__ void stage_tile_256(const ushort_t* gA, const ushort_t* gB,
                                               ushort_t* lA, ushort_t* lB, int K) {
    #pragma unroll
    for (int c = 0; c < 4; c++) {
        load_lds16(gA + (size_t)(8 * c) * K, lA + (8 * c) * 64);
        load_lds16(gB + (size_t)(8 * c) * K, lB + (8 * c) * 64);
    }
}

__device__ __forceinline__ void compute_tile_256(const ushort_t* __restrict__ As_,
                                                 const ushort_t* __restrict__ Bs_,
                                                 f32x4 (&acc)[8][4],
                                                 int wm, int wn, int fm, int fk, int swz) {
    bf16x8 bfr[4][2];
    #pragma unroll
    for (int j = 0; j < 4; j++)
        #pragma unroll
        for (int kh = 0; kh < 2; kh++)
            bfr[j][kh] = *(const bf16x8*)&Bs_[(wn + 16 * j + fm) * 64 + ((kh * 32 + fk) ^ swz)];

    __builtin_amdgcn_s_setprio(1);
    #pragma unroll
    for (int ph = 0; ph < 4; ph++) {
        bf16x8 af[2][2];
        #pragma unroll
        for (int i = 0; i < 2; i++)
            #pragma unroll
            for (int kh = 0; kh < 2; kh++)
                af[i][kh] = *(const bf16x8*)&As_[(wm + 16 * (2 * ph + i) + fm) * 64 + ((kh * 32 + fk) ^ swz)];
        #pragma unroll
        for (int kh = 0; kh < 2; kh++)
            #pragma unroll
            for (int i = 0; i < 2; i++)
                #pragma unroll
                for (int j = 0; j < 4; j++)
                    acc[2 * ph + i][j] = __builtin_amdgcn_mfma_f32_16x16x32_bf16(
                        af[i][kh], bfr[j][kh], acc[2 * ph + i][j], 0, 0, 0);
    }
    __builtin_amdgcn_s_setprio(0);
}

__device__ __forceinline__ void kloop_256(const ushort_t*& gA, const ushort_t*& gB,
                                          ushort_t (*As)[256 * 64], ushort_t (*Bs)[256 * 64],
                                          int lbase, int K, int NT,
                                          f32x4 (&acc)[8][4],
                                          int wm, int wn, int fm, int fk, int swz) {
    stage_tile_256(gA, gB, &As[0][lbase], &Bs[0][lbase], K);
    gA += 64; gB += 64;

    for (int t = 0; t < NT; t += 2) {
        stage_tile_256(gA, gB, &As[1][lbase], &Bs[1][lbase], K);
        gA += 64; gB += 64;
        asm volatile("s_waitcnt vmcnt(8)" ::: "memory");
        __builtin_amdgcn_s_barrier();
        asm volatile("" ::: "memory");

        compute_tile_256(&As[0][0], &Bs[0][0], acc, wm, wn, fm, fk, swz);

        asm volatile("s_waitcnt lgkmcnt(0)" ::: "memory");
        __builtin_amdgcn_sched_barrier(0);
        __builtin_amdgcn_s_barrier();
        asm volatile("" ::: "memory");

        if (t + 2 < NT) {
            stage_tile_256(gA, gB, &As[0][lbase], &Bs[0][lbase], K);
            gA += 64; gB += 64;
            asm volatile("s_waitcnt vmcnt(8)" ::: "memory");
        } else {
            asm volatile("s_waitcnt vmcnt(0)" ::: "memory");
        }
        __builtin_amdgcn_s_barrier();
        asm volatile("" ::: "memory");

        compute_tile_256(&As[1][0], &Bs[1][0], acc, wm, wn, fm, fk, swz);

        asm volatile("s_waitcnt lgkmcnt(0)" ::: "memory");
        __builtin_amdgcn_sched_barrier(0);
        __builtin_amdgcn_s_barrier();
        asm volatile("" ::: "memory");
    }
}

template<bool RELU, int OUTMODE>
__global__ __launch_bounds__(512, 2) void gemm_mfma_256(const ushort_t* __restrict__ A,
                                                        const ushort_t* __restrict__ Bt,
                                                        const float* __restrict__ bias,
                                                        const float* __restrict__ resid,
                                                        void* __restrict__ Cout,
                                                        int M, int N, int K) {
    __shared__ ushort_t As[2][256 * 64];   // 64 KiB
    __shared__ ushort_t Bs[2][256 * 64];   // 64 KiB

    int tid = threadIdx.x;
    int wave = tid >> 6, lane = tid & 63;
    int m0 = blockIdx.x * 256, n0 = blockIdx.y * 256;
    int l8 = lane >> 3, c8 = lane & 7;
    int cg = c8 ^ l8;

    const ushort_t* gA = A  + (size_t)(m0 + 32 * wave + l8) * K + cg * 8;
    const ushort_t* gB = Bt + (size_t)(n0 + 32 * wave + l8) * K + cg * 8;
    const int lbase = (32 * wave) * 64;

    f32x4 acc[8][4];
    #pragma unroll
    for (int i = 0; i < 8; i++)
        #pragma unroll
        for (int j = 0; j < 4; j++) acc[i][j] = (f32x4){0.f, 0.f, 0.f, 0.f};

    int wr = wave >> 2, wc = wave & 3;           // 2 x 4 wave grid
    int wm = wr * 128, wn = wc * 64;             // per-wave 128x64 output
    int fm = lane & 15;
    int fk = (lane >> 4) * 8;
    int swz = (fm & 7) * 8;

    kloop_256(gA, gB, As, Bs, lbase, K, K >> 6, acc, wm, wn, fm, fk, swz);

    int col_l = lane & 15, row_l = (lane >> 4) * 4;
    #pragma unroll
    for (int i = 0; i < 8; i++) {
        #pragma unroll
        for (int j = 0; j < 4; j++) {
            int col = n0 + wn + 16 * j + col_l;
            float bia = bias ? bias[col] : 0.f;
            #pragma unroll
            for (int r = 0; r < 4; r++) {
                int row = m0 + wm + 16 * i + row_l + r;
                float c = acc[i][j][r] + bia;
                if (RELU) c = fmaxf(c, 0.f);
                if (resid) c += resid[(size_t)row * N + col];
                if (OUTMODE == 1)
                    ((ushort_t*)Cout)[(size_t)row * N + col] = f2bf(c);
                else
                    ((float*)Cout)[(size_t)row * N + col] = c;
            }
        }
    }
}

// ============ split-K variant of the pipelined 256x256 GEMM (bf16 partials) ============
// grid: (M/256, N/256, nsplit); (K/nsplit) % 128 == 0.
__global__ __launch_bounds__(512, 2) void gemm_splitk_256(const ushort_t* __restrict__ A,
                                                          const ushort_t* __restrict__ Bt,
                                                          ushort_t* __restrict__ P,
                                                          int M, int N, int K, int nsplit) {
    __shared__ ushort_t As[2][256 * 64];
    __shared__ ushort_t Bs[2][256 * 64];

    int tid = threadIdx.x;
    int wave = tid >> 6, lane = tid & 63;
    int m0 = blockIdx.x * 256, n0 = blockIdx.y * 256;
    int klen = K / nsplit, kbeg = blockIdx.z * klen;
    int l8 = lane >> 3, c8 = lane & 7;
    int cg = c8 ^ l8;

    const ushort_t* gA = A  + (size_t)(m0 + 32 * wave + l8) * K + kbeg + cg * 8;
    const ushort_t* gB = Bt + (size_t)(n0 + 32 * wave + l8) * K + kbeg + cg * 8;
    const int lbase = (32 * wave) * 64;

    f32x4 acc[8][4];
    #pragma unroll
    for (int i = 0; i < 8; i++)
        #pragma unroll
        for (int j = 0; j < 4; j++) acc[i][j] = (f32x4){0.f, 0.f, 0.f, 0.f};

    int wr = wave >> 2, wc = wave & 3;
    int wm = wr * 128, wn = wc * 64;
    int fm = lane & 15;
    int fk = (lane >> 4) * 8;
    int swz = (fm & 7) * 8;

    kloop_256(gA, gB, As, Bs, lbase, K, klen >> 6, acc, wm, wn, fm, fk, swz);

    ushort_t* Pz = P + (size_t)blockIdx.z * M * N;
    int col_l = lane & 15, row_l = (lane >> 4) * 4;
    #pragma unroll
    for (int i = 0; i < 8; i++) {
        #pragma unroll
        for (int j = 0; j < 4; j++) {
            int col = n0 + wn + 16 * j + col_l;
            #pragma unroll
            for (int r = 0; r < 4; r++) {
                int row = m0 + wm + 16 * i + row_l + r;
                Pz[(size_t)row * N + col] = f2bf(acc[i][j][r]);
            }
        }
    }
}

// out = sum_z P[z] + x2 + b2   (4 partials)
__global__ __launch_bounds__(256) void ffn2_reduce(const ushort_t* __restrict__ P,
                                                   const float* __restrict__ x2,
                                                   const float* __restrict__ b2,
                                                   float* __restrict__ out) {
    int row = blockIdx.x, t = threadIdx.x;
    const size_t MN = (size_t)ROWS * D_MODEL;
    size_t off = (size_t)row * D_MODEL + (t << 2);
    float4 acc = *(const float4*)&x2[off];
    float4 bb  = *(const float4*)&b2[t << 2];
    acc.x += bb.x; acc.y += bb.y; acc.z += bb.z; acc.w += bb.w;
    #pragma unroll
    for (int s = 0; s < 4; s++) {
        ushort4 u = *(const ushort4*)&P[s * MN + off];
        acc.x += bf2f(u.x); acc.y += bf2f(u.y);
        acc.z += bf2f(u.z); acc.w += bf2f(u.w);
    }
    *(float4*)&out[off] = acc;
}

// ---------------- bf16 MFMA GEMM, 128x64 tile, BK=64 (grid: M/128, N/64) ----------
// High-occupancy small-N GEMM (512 blocks) — used for the WO projection.
// Single-buffered by design (R9 lesson: dbuf neutral here, inter-block overlap suffices).
template<bool RELU>
__global__ __launch_bounds__(256) void gemm_mfma_64(const ushort_t* __restrict__ A,
                                                    const ushort_t* __restrict__ Bt,
                                                    const float* __restrict__ bias,
                                                    const float* __restrict__ resid,
                                                    float* __restrict__ Cout,
                                                    int M, int N, int K) {
    __shared__ ushort_t As[128 * 64];
    __shared__ ushort_t Bs[64 * 64];

    int tid = threadIdx.x;
    int wave = tid >> 6, lane = tid & 63;
    int m0 = blockIdx.x * 128, n0 = blockIdx.y * 64;
    int l8 = lane >> 3, c8 = lane & 7;
    int cg = c8 ^ l8;

    const ushort_t* gA = A  + (size_t)(m0 + 32 * wave + l8) * K + cg * 8;
    const ushort_t* gB = Bt + (size_t)(n0 + 16 * wave + l8) * K + cg * 8;
    ushort_t* lA = As + (32 * wave) * 64;
    ushort_t* lB = Bs + (16 * wave) * 64;

    f32x4 acc[2][4];
    #pragma unroll
    for (int i = 0; i < 2; i++)
        #pragma unroll
        for (int j = 0; j < 4; j++) acc[i][j] = (f32x4){0.f, 0.f, 0.f, 0.f};

    int wm = 32 * wave;
    int fm = lane & 15;
    int fk = (lane >> 4) * 8;
    int swz = (fm & 7) * 8;

    for (int k0 = 0; k0 < K; k0 += 64) {
        __syncthreads();
        #pragma unroll
        for (int c = 0; c < 4; c++)
            load_lds16(gA + (size_t)(8 * c) * K, lA + (8 * c) * 64);
        #pragma unroll
        for (int c = 0; c < 2; c++)
            load_lds16(gB + (size_t)(8 * c) * K, lB + (8 * c) * 64);
        gA += 64; gB += 64;
        __syncthreads();

        #pragma unroll
        for (int kh = 0; kh < 2; kh++) {
            int kk = kh * 32;
            bf16x8 af[2], bfr[4];
            #pragma unroll
            for (int i = 0; i < 2; i++)
                af[i] = *(const bf16x8*)&As[(wm + 16 * i + fm) * 64 + ((kk + fk) ^ swz)];
            #pragma unroll
            for (int j = 0; j < 4; j++)
                bfr[j] = *(const bf16x8*)&Bs[(16 * j + fm) * 64 + ((kk + fk) ^ swz)];
            #pragma unroll
            for (int i = 0; i < 2; i++)
                #pragma unroll
                for (int j = 0; j < 4; j++)
                    acc[i][j] = __builtin_amdgcn_mfma_f32_16x16x32_bf16(af[i], bfr[j], acc[i][j], 0, 0, 0);
        }
    }

    int col_l = lane & 15, row_l = (lane >> 4) * 4;
    #pragma unroll
    for (int i = 0; i < 2; i++) {
        #pragma unroll
        for (int j = 0; j < 4; j++) {
            int col = n0 + 16 * j + col_l;
            float bia = bias ? bias[col] : 0.f;
            #pragma unroll
            for (int r = 0; r < 4; r++) {
                int row = m0 + wm + 16 * i + row_l + r;
                float c = acc[i][j][r] + bia;
                if (RELU) c = fmaxf(c, 0.f);
                if (resid) c += resid[(size_t)row * N + col];
                Cout[(size_t)row * N + col] = c;
            }
        }
    }
}

// ---------------- MFMA flash attention over COMPACTED keys, S^T form ----------------
// R12: QBLK 128 -> 64. fattn was GRID-limited (512 blocks = 2/CU while LDS allowed 3);
// halving the Q-tile doubles the grid to 1024 blocks, and shrinking Pt (64 rows,
// 16B-chunk XOR swizzle instead of +4 pad) brings LDS to exactly 40960 B -> 4 blocks/CU.
// Sync skeleton unchanged from the verified R8 form (stage t+1 -> vmcnt(4) -> barrier ->
// compute -> lgkmcnt(0)+sched_barrier -> barrier). Pt rows remain wave-private.
__global__ __launch_bounds__(256) void fattn_mfma(const ushort_t* __restrict__ Q,
                                                  const ushort_t* __restrict__ K2,
                                                  const ushort_t* __restrict__ Vt2,
                                                  const int* __restrict__ nunb,
                                                  ushort_t* __restrict__ O) {
    __shared__ ushort_t Ks[2][64 * 64];   // [k][d], chunk-swizzled, double-buffered (16 KiB)
    __shared__ ushort_t Vs[2][64 * 64];   // [d][k], chunk-swizzled, double-buffered (16 KiB)
    __shared__ ushort_t Pt[64 * 64];      // [q][k], 16B-chunk XOR swizzle (8 KiB); wave-private

    int tid = threadIdx.x, wave = tid >> 6, lane = tid & 63;
    int qt = blockIdx.x, h = blockIdx.y, b = blockIdx.z;
    int q0 = qt * 64;
    int l8 = lane >> 3, c8 = lane & 7;
    int cg = c8 ^ l8;

    const int nun = nunb[b];
    const int ntiles = (nun + 63) >> 6;

    const ushort_t* Kg = K2 + ((size_t)(b * SEQ)) * D_MODEL + h * 64;
    const ushort_t* Vg = Vt2 + ((size_t)(b * 1024 + h * 64)) * SEQ;

    int fm = lane & 15, fq = lane >> 4;
    int fk = fq * 8;
    int swz = (fm & 7) * 8;
    const float C2 = 0.18033688f;       // 0.125 * log2(e)

    // this wave's 16 q-rows; Pt row base + chunk-swizzle key (wave-private)
    int prow = (wave * 16 + fm) * 64;   // ushort index of row base
    int psw  = fm & 7;                  // 16B-chunk XOR key

    bf16x8 qf[2];
    {
        int row = q0 + wave * 16 + fm;
        const ushort_t* qr = Q + (size_t)(b * SEQ + row) * D_MODEL + h * 64;
        qf[0] = *(const bf16x8*)&qr[fk];
        qf[1] = *(const bf16x8*)&qr[32 + fk];
    }

    float l_acc = 0.f;
    f32x4 acc_o[4];
    #pragma unroll
    for (int j = 0; j < 4; j++) acc_o[j] = (f32x4){0.f, 0.f, 0.f, 0.f};

    // 4 global_load_lds per thread per stage (2 x {K,V})
    #define FATTN_STAGE(KT, BUF)                                                            \
        {                                                                                   \
            int k0s = (KT) * 64;                                                            \
            _Pragma("unroll")                                                               \
            for (int c = 0; c < 2; c++) {                                                   \
                int row = c * 32 + wave * 8 + l8;                                           \
                load_lds16(Kg + (size_t)(k0s + row) * D_MODEL + cg * 8,                     \
                           &Ks[BUF][(c * 32 + wave * 8) * 64]);                             \
                load_lds16(Vg + (size_t)row * SEQ + k0s + cg * 8,                           \
                           &Vs[BUF][(c * 32 + wave * 8) * 64]);                             \
            }                                                                               \
        }

    // prologue: stage tile 0 into buf0 (first iteration's vmcnt covers the wait)
    FATTN_STAGE(0, 0)

    for (int kt = 0; kt < ntiles; kt++) {
        int cur = kt & 1;
        int k0 = kt * 64;
        if (kt + 1 < ntiles) {                      // block-uniform branch
            FATTN_STAGE(kt + 1, cur ^ 1)
            asm volatile("s_waitcnt vmcnt(4)" ::: "memory");   // oldest 4 (tile kt) done
        } else {
            asm volatile("s_waitcnt vmcnt(0)" ::: "memory");
        }
        __builtin_amdgcn_s_barrier();
        asm volatile("" ::: "memory");

        f32x4 sT[4];
        #pragma unroll
        for (int jk = 0; jk < 4; jk++) sT[jk] = (f32x4){0.f, 0.f, 0.f, 0.f};
        #pragma unroll
        for (int kh = 0; kh < 2; kh++) {
            bf16x8 kf[4];
            #pragma unroll
            for (int jk = 0; jk < 4; jk++)
                kf[jk] = *(const bf16x8*)&Ks[cur][(16 * jk + fm) * 64 + ((kh * 32 + fk) ^ swz)];
            #pragma unroll
            for (int jk = 0; jk < 4; jk++)
                sT[jk] = __builtin_amdgcn_mfma_f32_16x16x32_bf16(kf[jk], qf[kh], sT[jk], 0, 0, 0);
        }

        if (k0 + 64 <= nun) {
            #pragma unroll
            for (int jk = 0; jk < 4; jk++) {
                #pragma unroll
                for (int r = 0; r < 4; r++) {
                    float p = exp2f(sT[jk][r] * C2);
                    sT[jk][r] = p;
                    l_acc += p;
                }
            }
        } else {
            #pragma unroll
            for (int jk = 0; jk < 4; jk++) {
                int kb = k0 + 16 * jk + 4 * fq;
                #pragma unroll
                for (int r = 0; r < 4; r++) {
                    float bias = (kb + r < nun) ? 0.f : -1000.f;
                    float p = exp2f(fmaf(sT[jk][r], C2, bias));
                    sT[jk][r] = p;
                    l_acc += p;
                }
            }
        }

        // pack P -> Pt (wave-private rows; 16B-chunk XOR swizzle, no barrier needed)
        // unswizzled write pos = 16*jk + 4*fq ushorts -> chunk 2*jk+(fq>>1), sub 4*(fq&1)
        #pragma unroll
        for (int jk = 0; jk < 4; jk++) {
            unsigned u0 = __float_as_uint(sT[jk][0]) + 0x8000u;
            unsigned u1 = __float_as_uint(sT[jk][1]) + 0x8000u;
            unsigned u2 = __float_as_uint(sT[jk][2]) + 0x8000u;
            unsigned u3 = __float_as_uint(sT[jk][3]) + 0x8000u;
            uint2 pk;
            pk.x = __builtin_amdgcn_perm(u1, u0, 0x07060302u);
            pk.y = __builtin_amdgcn_perm(u3, u2, 0x07060302u);
            int cw = 2 * jk + (fq >> 1);
            *(uint2*)&Pt[prow + ((cw ^ psw) << 3) + (fq & 1) * 4] = pk;
        }

        #pragma unroll
        for (int kh = 0; kh < 2; kh++) {
            bf16x8 vf[4];
            #pragma unroll
            for (int j = 0; j < 4; j++)
                vf[j] = *(const bf16x8*)&Vs[cur][(16 * j + fm) * 64 + ((kh * 32 + fk) ^ swz)];
            // unswizzled read pos = kh*32 + fq*8 ushorts -> chunk 4*kh+fq, full 16B
            int cr = 4 * kh + fq;
            bf16x8 pf = *(const bf16x8*)&Pt[prow + ((cr ^ psw) << 3)];
            #pragma unroll
            for (int j = 0; j < 4; j++)
                acc_o[j] = __builtin_amdgcn_mfma_f32_16x16x32_bf16(pf, vf[j], acc_o[j], 0, 0, 0);
        }

        // release buf[cur] for overwrite in iteration kt+1 (stage of tile kt+2)
        asm volatile("s_waitcnt lgkmcnt(0)" ::: "memory");
        __builtin_amdgcn_sched_barrier(0);
        __builtin_amdgcn_s_barrier();
        asm volatile("" ::: "memory");
    }
    #undef FATTN_STAGE

    {
        float l_full = l_acc;
        l_full += __shfl_xor(l_full, 16);
        l_full += __shfl_xor(l_full, 32);
        #pragma unroll
        for (int r = 0; r < 4; r++) {
            float lr = __shfl(l_full, fq * 4 + r);
            float inv = 1.0f / lr;
            int row = q0 + wave * 16 + fq * 4 + r;
            #pragma unroll
            for (int j = 0; j < 4; j++) {
                int col = h * 64 + 16 * j + fm;
                O[(size_t)(b * SEQ + row) * D_MODEL + col] = f2bf(acc_o[j][r] * inv);
            }
        }
    }
}

// ---------------- launch ----------------
extern "C" void kernel_launch(void* const* d_in, const int* in_sizes, int n_in,
                              void* d_out, int out_size, void* d_ws, size_t ws_size,
                              hipStream_t stream) {
    const float* x    = (const float*)d_in[0];
    const int*   mask = (const int*)  d_in[1];
    const float* wq   = (const float*)d_in[2];
    const float* wk   = (const float*)d_in[3];
    const float* wv   = (const float*)d_in[4];
    const float* wo   = (const float*)d_in[5];
    const float* w1   = (const float*)d_in[6];
    const float* b1   = (const float*)d_in[7];
    const float* w2   = (const float*)d_in[8];
    const float* b2   = (const float*)d_in[9];
    const float* ln1a = (const float*)d_in[10];
    const float* ln1b = (const float*)d_in[11];
    const float* ln2a = (const float*)d_in[12];
    const float* ln2b = (const float*)d_in[13];
    float* out = (float*)d_out;

    char* ws = (char*)d_ws;
    const size_t MB = 1024 * 1024;
    float*    x2    = (float*)   (ws + 0 * MB);    // 16 MB (hosts K2/Vt2 pre-WO)
    ushort_t* K2    = (ushort_t*)(ws + 0 * MB);    // 8 MB  (dead before x2 written)
    ushort_t* Vt2   = (ushort_t*)(ws + 8 * MB);    // 8 MB
    ushort_t* hbf   = (ushort_t*)(ws + 16 * MB);   // 8 MB (LN1/attn/LN2 out)
    ushort_t* qbf   = (ushort_t*)(ws + 24 * MB);   // 8 MB
    ushort_t* ffbf  = (ushort_t*)(ws + 48 * MB);   // 32 MB (FFN1 out)
    ushort_t* wqkvt = (ushort_t*)(ws + 80 * MB);   // 6 MB: wq|wk|wv transposed
    ushort_t* wot   = (ushort_t*)(ws + 86 * MB);   // 2 MB
    ushort_t* w1t   = (ushort_t*)(ws + 88 * MB);   // 8 MB
    ushort_t* w2t   = (ushort_t*)(ws + 96 * MB);   // 8 MB
    int*      idxb  = (int*)     (ws + 104 * MB);
    int*      nunb  = (int*)     (ws + 104 * MB + 64 * 1024);
    ushort_t* pbuf  = (ushort_t*)(ws + 16 * MB);   // 32 MB splitk partials (reuse 16..48,
                                                   //   hbf/qbf dead by FFN2 time)

    ushort_t* wqt = wqkvt;
    ushort_t* wkt = wqkvt + (size_t)1024 * 1024;
    ushort_t* wvt = wqkvt + (size_t)2 * 1024 * 1024;

    dim3 blk(256);
    dim3 blk512(512);

    transpose4_bf16_kernel<<<dim3(16, 16, 4), blk, 0, stream>>>(wq, wk, wv, wo, wqt, wkt, wvt, wot);
    transpose_ffn_kernel<<<dim3(1024, 2), blk, 0, stream>>>(w1, w2, w1t, w2t);
    mask_scan_kernel<<<BATCH, blk, 0, stream>>>(mask, idxb, nunb);

    ln_kernel<<<ROWS, blk, 0, stream>>>(x, ln1a, ln1b, hbf);

    // unified QKV: 128^2 tile, ~528 active blocks; K/V rows gathered in-place via idx
    gemm_qkv<<<dim3(32, 24), blk, 0, stream>>>(hbf, wqkvt, idxb, nunb, qbf, K2, Vt2);

    // fattn: QBLK=64 -> 1024 blocks = 4/CU (grid-limit fix); LDS 40960 B
    dim3 g_attn(SEQ / 64, NUM_HEADS, BATCH);
    fattn_mfma<<<g_attn, blk, 0, stream>>>(qbf, K2, Vt2, nunb, hbf);

    // x2 = x + attn @ wo — 128x64 tile, 512 blocks (N=1024 too small for the 256^2 template)
    dim3 g_wo(ROWS / 128, D_MODEL / 64);
    gemm_mfma_64<false><<<g_wo, blk, 0, stream>>>(hbf, wot, nullptr, x, x2, ROWS, D_MODEL, D_MODEL);

    ln_kernel<<<ROWS, blk, 0, stream>>>(x2, ln2a, ln2b, hbf);

    // ff = relu(h2 @ w1 + b1) — verified pipelined 256^2 template (256 blocks = 1/CU)
    dim3 g_ff1(ROWS / 256, D_HIDDEN / 256);
    gemm_mfma_256<true, 1><<<g_ff1, blk512, 0, stream>>>(hbf, w1t, b1, nullptr, ffbf,
                                                         ROWS, D_HIDDEN, D_MODEL);

    // FFN2: pipelined 256x256 split-K=4 + fused reduce (grid 16x4x4 = 256 blocks = 1/CU)
    dim3 g_ff2(ROWS / 256, D_MODEL / 256, 4);
    gemm_splitk_256<<<g_ff2, blk512, 0, stream>>>(ffbf, w2t, pbuf, ROWS, D_MODEL, D_HIDDEN, 4);
    ffn2_reduce<<<ROWS, blk, 0, stream>>>(pbuf, x2, b2, out);
}

// Round 14
// 328.405 us; speedup vs baseline: 1.0149x; 1.0149x over previous
//
#include <hip/hip_runtime.h>
#include <math.h>

#define D_MODEL 1024
#define D_HIDDEN 4096
#define NUM_HEADS 16
#define D_K 64
#define EPS 1e-6f
#define MASK_FILL -1e9f
#define BATCH 2
#define SEQ 2048
#define ROWS (BATCH * SEQ)   // 4096

typedef unsigned short ushort_t;
typedef __attribute__((ext_vector_type(8))) short bf16x8;
typedef __attribute__((ext_vector_type(4))) float f32x4;

__device__ __forceinline__ unsigned short f2bf(float f) {
    union { float f; unsigned int u; } v; v.f = f;
    unsigned int r = v.u + 0x7fffu + ((v.u >> 16) & 1u);   // RNE
    return (unsigned short)(r >> 16);
}
__device__ __forceinline__ float bf2f(unsigned short u) {
    union { unsigned int u; float f; } v; v.u = ((unsigned int)u) << 16;
    return v.f;
}

__device__ __forceinline__ void load_lds16(const void* g, void* l) {
    __builtin_amdgcn_global_load_lds(
        (__attribute__((address_space(1))) void*)g,
        (__attribute__((address_space(3))) void*)l,
        16, 0, 0);
}

// ---------------- LayerNorm ----------------
__global__ __launch_bounds__(256) void ln_kernel(const float* __restrict__ x,
                                                 const float* __restrict__ a,
                                                 const float* __restrict__ b,
                                                 ushort_t* __restrict__ out) {
    int row = blockIdx.x;
    int t = threadIdx.x;
    const float* xr = x + (size_t)row * D_MODEL;

    float4 v = ((const float4*)xr)[t];
    float s  = v.x + v.y + v.z + v.w;
    float ss = v.x*v.x + v.y*v.y + v.z*v.z + v.w*v.w;
    #pragma unroll
    for (int o = 32; o > 0; o >>= 1) {
        s  += __shfl_down(s,  o);
        ss += __shfl_down(ss, o);
    }
    __shared__ float ws0[4], ws1[4];
    __shared__ float mean_s, inv_s;
    int wid = t >> 6, lane = t & 63;
    if (lane == 0) { ws0[wid] = s; ws1[wid] = ss; }
    __syncthreads();
    if (t == 0) {
        float S1 = ws0[0] + ws0[1] + ws0[2] + ws0[3];
        float S2 = ws1[0] + ws1[1] + ws1[2] + ws1[3];
        float mean = S1 / (float)D_MODEL;
        float var  = (S2 - mean * S1) / (float)(D_MODEL - 1);  // Bessel
        mean_s = mean;
        inv_s  = 1.0f / (sqrtf(var) + EPS);
    }
    __syncthreads();
    float mean = mean_s, inv = inv_s;
    float4 av = ((const float4*)a)[t];
    float4 bv = ((const float4*)b)[t];
    ushort4 o;
    o.x = f2bf(av.x * (v.x - mean) * inv + bv.x);
    o.y = f2bf(av.y * (v.y - mean) * inv + bv.y);
    o.z = f2bf(av.z * (v.z - mean) * inv + bv.z);
    o.w = f2bf(av.w * (v.w - mean) * inv + bv.w);
    *(ushort4*)&out[(size_t)row * D_MODEL + (t << 2)] = o;
}

// ---------------- weight transpose fp32->bf16: W[K][N] -> Wt[N][K] ----------------
__device__ __forceinline__ void transpose_tile(const float* W, ushort_t* Wt,
                                               int K, int N, int n0, int k0) {
    __shared__ float tile[64][65];
    int t = threadIdx.x;
    int c4 = t & 15, r = t >> 4;
    #pragma unroll
    for (int p = 0; p < 4; p++) {
        int row = r + 16 * p;
        float4 v = *(const float4*)&W[(size_t)(k0 + row) * N + n0 + 4 * c4];
        tile[row][4*c4+0] = v.x; tile[row][4*c4+1] = v.y;
        tile[row][4*c4+2] = v.z; tile[row][4*c4+3] = v.w;
    }
    __syncthreads();
    #pragma unroll
    for (int p = 0; p < 4; p++) {
        int n = r + 16 * p;
        ushort4 o;
        o.x = f2bf(tile[4*c4+0][n]);
        o.y = f2bf(tile[4*c4+1][n]);
        o.z = f2bf(tile[4*c4+2][n]);
        o.w = f2bf(tile[4*c4+3][n]);
        *(ushort4*)&Wt[(size_t)(n0 + n) * K + k0 + 4 * c4] = o;
    }
}

__global__ __launch_bounds__(256) void transpose4_bf16_kernel(const float* s0, const float* s1,
                                                              const float* s2, const float* s3,
                                                              ushort_t* d0, ushort_t* d1,
                                                              ushort_t* d2, ushort_t* d3) {
    const float* S[4] = {s0, s1, s2, s3};
    ushort_t*    D[4] = {d0, d1, d2, d3};
    int z = blockIdx.z;
    transpose_tile(S[z], D[z], D_MODEL, D_MODEL, blockIdx.x * 64, blockIdx.y * 64);
}

__global__ __launch_bounds__(256) void transpose_ffn_kernel(const float* w1, const float* w2,
                                                            ushort_t* w1t, ushort_t* w2t) {
    int lin = blockIdx.x;
    if (blockIdx.y == 0)
        transpose_tile(w1, w1t, D_MODEL, D_HIDDEN, (lin & 63) * 64, (lin >> 6) * 64);
    else
        transpose_tile(w2, w2t, D_HIDDEN, D_MODEL, (lin & 15) * 64, (lin >> 4) * 64);
}

// ---------------- mask prefix scan ----------------
__global__ __launch_bounds__(256) void mask_scan_kernel(const int* __restrict__ mask,
                                                        int* __restrict__ idx,
                                                        int* __restrict__ nun) {
    int b = blockIdx.x, t = threadIdx.x;
    __shared__ int sums[256];
    const int* m = mask + b * SEQ;
    int loc[8], s = 0;
    #pragma unroll
    for (int i = 0; i < 8; i++) { loc[i] = m[t * 8 + i]; s += loc[i]; }
    sums[t] = s;
    __syncthreads();
    for (int off = 1; off < 256; off <<= 1) {
        int v = sums[t];
        if (t >= off) v += sums[t - off];
        __syncthreads();
        sums[t] = v;
        __syncthreads();
    }
    int c = (t > 0) ? sums[t - 1] : 0;
    #pragma unroll
    for (int i = 0; i < 8; i++)
        if (loc[i]) { idx[b * SEQ + c] = t * 8 + i; c++; }
    if (t == 255) nun[b] = sums[255];
}

// ======== BK=64 staging/read pattern (fattn-style, 128B LDS rows, XOR swizzle) =====
// Stage: wave stages 32 rows per tile; lane l -> row sub l>>3, global chunk (l&7)^(l>>3).
// Read: row r chunk c lives at LDS chunk c ^ (r&7)  -> conflict-free.

// ---------------- unified QKV GEMM, K/V rows gathered in-place via idx ----------------
// R11 (verified): hgather folded into A addressing; per-thread row pointers hoisted to
// the prologue; tail rows clamp to idx[nun-1] (P contribution exp2(-1000)=0 exactly).
// Single-buffered by design: 32 KiB LDS -> 4-5 blocks/CU; inter-block wave overlap hides
// the staging stall (R9 lesson: explicit dbuf here costs occupancy for zero net gain).
__global__ __launch_bounds__(256) void gemm_qkv(const ushort_t* __restrict__ h,
                                                const ushort_t* __restrict__ Wt,   // [3072][1024]
                                                const int* __restrict__ idx,
                                                const int* __restrict__ nunb,
                                                ushort_t* __restrict__ Qout,
                                                ushort_t* __restrict__ K2,
                                                ushort_t* __restrict__ Vt2) {
    __shared__ ushort_t As[128 * 64];
    __shared__ ushort_t Bs[128 * 64];
    const int K = D_MODEL;

    int bx = blockIdx.x, by = blockIdx.y;
    bool isQ = (by < 8);
    int b = bx >> 4;
    int n0 = isQ ? by * 128 : (by - 8) * 128;
    int m0;
    int nun = 0;
    if (isQ) {
        m0 = bx * 128;
    } else {
        nun = nunb[b];
        int mloc = (bx & 15) * 128;
        if (mloc >= ((nun + 127) & ~127)) return;   // block-uniform early exit (pre-barrier)
        m0 = mloc;
    }
    const ushort_t* Bt = Wt + (size_t)(isQ ? 0 : 1024) * K;

    int tid = threadIdx.x;
    int wave = tid >> 6, lane = tid & 63;
    int l8 = lane >> 3, c8 = lane & 7;
    int cg = c8 ^ l8;

    // Per-thread A-row base pointers (4 rows, fixed across K-tiles).
    const ushort_t* gA_c[4];
    #pragma unroll
    for (int c = 0; c < 4; c++) {
        int r = m0 + 32 * wave + l8 + 8 * c;
        int grow;
        if (isQ) {
            grow = r;                                // global row over both batches
        } else {
            int rc = (r < nun) ? r : (nun - 1);      // clamp tail to a valid row
            grow = b * SEQ + idx[b * SEQ + rc];      // gathered unmasked row
        }
        gA_c[c] = h + (size_t)grow * K + cg * 8;
    }
    const ushort_t* gB = Bt + (size_t)(n0 + 32 * wave + l8) * K + cg * 8;
    ushort_t* lA = As + (32 * wave) * 64;
    ushort_t* lB = Bs + (32 * wave) * 64;

    f32x4 acc[4][4];
    #pragma unroll
    for (int i = 0; i < 4; i++)
        #pragma unroll
        for (int j = 0; j < 4; j++) acc[i][j] = (f32x4){0.f, 0.f, 0.f, 0.f};

    int wm = (wave >> 1) * 64, wn = (wave & 1) * 64;
    int fm = lane & 15;
    int fk = (lane >> 4) * 8;
    int swz = (fm & 7) * 8;

    for (int k0 = 0; k0 < K; k0 += 64) {
        __syncthreads();
        #pragma unroll
        for (int c = 0; c < 4; c++) {
            load_lds16(gA_c[c] + k0,                    lA + (8 * c) * 64);
            load_lds16(gB + (size_t)(8 * c) * K + k0,   lB + (8 * c) * 64);
        }
        __syncthreads();

        #pragma unroll
        for (int kh = 0; kh < 2; kh++) {
            int kk = kh * 32;
            bf16x8 af[4], bfr[4];
            #pragma unroll
            for (int i = 0; i < 4; i++)
                af[i] = *(const bf16x8*)&As[(wm + 16 * i + fm) * 64 + ((kk + fk) ^ swz)];
            #pragma unroll
            for (int j = 0; j < 4; j++)
                bfr[j] = *(const bf16x8*)&Bs[(wn + 16 * j + fm) * 64 + ((kk + fk) ^ swz)];
            #pragma unroll
            for (int i = 0; i < 4; i++)
                #pragma unroll
                for (int j = 0; j < 4; j++)
                    acc[i][j] = __builtin_amdgcn_mfma_f32_16x16x32_bf16(af[i], bfr[j], acc[i][j], 0, 0, 0);
        }
    }

    int col_l = lane & 15, row_l = (lane >> 4) * 4;
    #pragma unroll
    for (int i = 0; i < 4; i++) {
        #pragma unroll
        for (int j = 0; j < 4; j++) {
            int col = n0 + wn + 16 * j + col_l;
            int row = m0 + wm + 16 * i + row_l;
            if (isQ) {
                #pragma unroll
                for (int r = 0; r < 4; r++)
                    Qout[(size_t)(row + r) * D_MODEL + col] = f2bf(acc[i][j][r]);
            } else if (col < 1024) {
                ushort_t* K2b = K2 + (size_t)b * SEQ * D_MODEL;
                #pragma unroll
                for (int r = 0; r < 4; r++)
                    K2b[(size_t)(row + r) * D_MODEL + col] = f2bf(acc[i][j][r]);
            } else {
                ushort_t* Vt2b = Vt2 + (size_t)b * D_MODEL * SEQ;
                ushort4 o;
                o.x = f2bf(acc[i][j][0]); o.y = f2bf(acc[i][j][1]);
                o.z = f2bf(acc[i][j][2]); o.w = f2bf(acc[i][j][3]);
                *(ushort4*)&Vt2b[(size_t)(col - 1024) * SEQ + row] = o;
            }
        }
    }
}

// ================= 256x256 8-wave double-buffered pipelined GEMM (VERIFIED R3/R7/R8) ===
// Grid must be >=256 blocks to fill the machine (1 block/CU at 128 KiB LDS) — do NOT use
// for small-N GEMMs (R6 lesson: WO at 64 blocks -> 4.9% occupancy, 3x regression).
// T3+T4: prefetch tile t+1 issued BEFORE waiting tile t; counted s_waitcnt vmcnt(8).
// T5: setprio(1) around MFMA cluster. T2: (row&7) chunk-XOR swizzle (0 bank conflicts).

__device__ __forceinline__ void stage_tile_256(const ushort_t* gA, const ushort_t* gB,
                                               ushort_t* lA, ushort_t* lB, int K) {
    #pragma unroll
    for (int c = 0; c < 4; c++) {
        load_lds16(gA + (size_t)(8 * c) * K, lA + (8 * c) * 64);
        load_lds16(gB + (size_t)(8 * c) * K, lB + (8 * c) * 64);
    }
}

__device__ __forceinline__ void compute_tile_256(const ushort_t* __restrict__ As_,
                                                 const ushort_t* __restrict__ Bs_,
                                                 f32x4 (&acc)[8][4],
                                                 int wm, int wn, int fm, int fk, int swz) {
    bf16x8 bfr[4][2];
    #pragma unroll
    for (int j = 0; j < 4; j++)
        #pragma unroll
        for (int kh = 0; kh < 2; kh++)
            bfr[j][kh] = *(const bf16x8*)&Bs_[(wn + 16 * j + fm) * 64 + ((kh * 32 + fk) ^ swz)];

    __builtin_amdgcn_s_setprio(1);
    #pragma unroll
    for (int ph = 0; ph < 4; ph++) {
        bf16x8 af[2][2];
        #pragma unroll
        for (int i = 0; i < 2; i++)
            #pragma unroll
            for (int kh = 0; kh < 2; kh++)
                af[i][kh] = *(const bf16x8*)&As_[(wm + 16 * (2 * ph + i) + fm) * 64 + ((kh * 32 + fk) ^ swz)];
        #pragma unroll
        for (int kh = 0; kh < 2; kh++)
            #pragma unroll
            for (int i = 0; i < 2; i++)
                #pragma unroll
                for (int j = 0; j < 4; j++)
                    acc[2 * ph + i][j] = __builtin_amdgcn_mfma_f32_16x16x32_bf16(
                        af[i][kh], bfr[j][kh], acc[2 * ph + i][j], 0, 0, 0);
    }
    __builtin_amdgcn_s_setprio(0);
}

__device__ __forceinline__ void kloop_256(const ushort_t*& gA, const ushort_t*& gB,
                                          ushort_t (*As)[256 * 64], ushort_t (*Bs)[256 * 64],
                                          int lbase, int K, int NT,
                                          f32x4 (&acc)[8][4],
                                          int wm, int wn, int fm, int fk, int swz) {
    stage_tile_256(gA, gB, &As[0][lbase], &Bs[0][lbase], K);
    gA += 64; gB += 64;

    for (int t = 0; t < NT; t += 2) {
        stage_tile_256(gA, gB, &As[1][lbase], &Bs[1][lbase], K);
        gA += 64; gB += 64;
        asm volatile("s_waitcnt vmcnt(8)" ::: "memory");
        __builtin_amdgcn_s_barrier();
        asm volatile("" ::: "memory");

        compute_tile_256(&As[0][0], &Bs[0][0], acc, wm, wn, fm, fk, swz);

        asm volatile("s_waitcnt lgkmcnt(0)" ::: "memory");
        __builtin_amdgcn_sched_barrier(0);
        __builtin_amdgcn_s_barrier();
        asm volatile("" ::: "memory");

        if (t + 2 < NT) {
            stage_tile_256(gA, gB, &As[0][lbase], &Bs[0][lbase], K);
            gA += 64; gB += 64;
            asm volatile("s_waitcnt vmcnt(8)" ::: "memory");
        } else {
            asm volatile("s_waitcnt vmcnt(0)" ::: "memory");
        }
        __builtin_amdgcn_s_barrier();
        asm volatile("" ::: "memory");

        compute_tile_256(&As[1][0], &Bs[1][0], acc, wm, wn, fm, fk, swz);

        asm volatile("s_waitcnt lgkmcnt(0)" ::: "memory");
        __builtin_amdgcn_sched_barrier(0);
        __builtin_amdgcn_s_barrier();
        asm volatile("" ::: "memory");
    }
}

template<bool RELU, int OUTMODE>
__global__ __launch_bounds__(512, 2) void gemm_mfma_256(const ushort_t* __restrict__ A,
                                                        const ushort_t* __restrict__ Bt,
                                                        const float* __restrict__ bias,
                                                        const float* __restrict__ resid,
                                                        void* __restrict__ Cout,
                                                        int M, int N, int K) {
    __shared__ ushort_t As[2][256 * 64];   // 64 KiB
    __shared__ ushort_t Bs[2][256 * 64];   // 64 KiB

    int tid = threadIdx.x;
    int wave = tid >> 6, lane = tid & 63;
    int m0 = blockIdx.x * 256, n0 = blockIdx.y * 256;
    int l8 = lane >> 3, c8 = lane & 7;
    int cg = c8 ^ l8;

    const ushort_t* gA = A  + (size_t)(m0 + 32 * wave + l8) * K + cg * 8;
    const ushort_t* gB = Bt + (size_t)(n0 + 32 * wave + l8) * K + cg * 8;
    const int lbase = (32 * wave) * 64;

    f32x4 acc[8][4];
    #pragma unroll
    for (int i = 0; i < 8; i++)
        #pragma unroll
        for (int j = 0; j < 4; j++) acc[i][j] = (f32x4){0.f, 0.f, 0.f, 0.f};

    int wr = wave >> 2, wc = wave & 3;           // 2 x 4 wave grid
    int wm = wr * 128, wn = wc * 64;             // per-wave 128x64 output
    int fm = lane & 15;
    int fk = (lane >> 4) * 8;
    int swz = (fm & 7) * 8;

    kloop_256(gA, gB, As, Bs, lbase, K, K >> 6, acc, wm, wn, fm, fk, swz);

    int col_l = lane & 15, row_l = (lane >> 4) * 4;
    #pragma unroll
    for (int i = 0; i < 8; i++) {
        #pragma unroll
        for (int j = 0; j < 4; j++) {
            int col = n0 + wn + 16 * j + col_l;
            float bia = bias ? bias[col] : 0.f;
            #pragma unroll
            for (int r = 0; r < 4; r++) {
                int row = m0 + wm + 16 * i + row_l + r;
                float c = acc[i][j][r] + bia;
                if (RELU) c = fmaxf(c, 0.f);
                if (resid) c += resid[(size_t)row * N + col];
                if (OUTMODE == 1)
                    ((ushort_t*)Cout)[(size_t)row * N + col] = f2bf(c);
                else
                    ((float*)Cout)[(size_t)row * N + col] = c;
            }
        }
    }
}

// ============ split-K variant of the pipelined 256x256 GEMM (bf16 partials) ============
// grid: (M/256, N/256, nsplit); (K/nsplit) % 128 == 0.
__global__ __launch_bounds__(512, 2) void gemm_splitk_256(const ushort_t* __restrict__ A,
                                                          const ushort_t* __restrict__ Bt,
                                                          ushort_t* __restrict__ P,
                                                          int M, int N, int K, int nsplit) {
    __shared__ ushort_t As[2][256 * 64];
    __shared__ ushort_t Bs[2][256 * 64];

    int tid = threadIdx.x;
    int wave = tid >> 6, lane = tid & 63;
    int m0 = blockIdx.x * 256, n0 = blockIdx.y * 256;
    int klen = K / nsplit, kbeg = blockIdx.z * klen;
    int l8 = lane >> 3, c8 = lane & 7;
    int cg = c8 ^ l8;

    const ushort_t* gA = A  + (size_t)(m0 + 32 * wave + l8) * K + kbeg + cg * 8;
    const ushort_t* gB = Bt + (size_t)(n0 + 32 * wave + l8) * K + kbeg + cg * 8;
    const int lbase = (32 * wave) * 64;

    f32x4 acc[8][4];
    #pragma unroll
    for (int i = 0; i < 8; i++)
        #pragma unroll
        for (int j = 0; j < 4; j++) acc[i][j] = (f32x4){0.f, 0.f, 0.f, 0.f};

    int wr = wave >> 2, wc = wave & 3;
    int wm = wr * 128, wn = wc * 64;
    int fm = lane & 15;
    int fk = (lane >> 4) * 8;
    int swz = (fm & 7) * 8;

    kloop_256(gA, gB, As, Bs, lbase, K, klen >> 6, acc, wm, wn, fm, fk, swz);

    ushort_t* Pz = P + (size_t)blockIdx.z * M * N;
    int col_l = lane & 15, row_l = (lane >> 4) * 4;
    #pragma unroll
    for (int i = 0; i < 8; i++) {
        #pragma unroll
        for (int j = 0; j < 4; j++) {
            int col = n0 + wn + 16 * j + col_l;
            #pragma unroll
            for (int r = 0; r < 4; r++) {
                int row = m0 + wm + 16 * i + row_l + r;
                Pz[(size_t)row * N + col] = f2bf(acc[i][j][r]);
            }
        }
    }
}

// out = sum_z P[z] + x2 + b2   (4 partials)
__global__ __launch_bounds__(256) void ffn2_reduce(const ushort_t* __restrict__ P,
                                                   const float* __restrict__ x2,
                                                   const float* __restrict__ b2,
                                                   float* __restrict__ out) {
    int row = blockIdx.x, t = threadIdx.x;
    const size_t MN = (size_t)ROWS * D_MODEL;
    size_t off = (size_t)row * D_MODEL + (t << 2);
    float4 acc = *(const float4*)&x2[off];
    float4 bb  = *(const float4*)&b2[t << 2];
    acc.x += bb.x; acc.y += bb.y; acc.z += bb.z; acc.w += bb.w;
    #pragma unroll
    for (int s = 0; s < 4; s++) {
        ushort4 u = *(const ushort4*)&P[s * MN + off];
        acc.x += bf2f(u.x); acc.y += bf2f(u.y);
        acc.z += bf2f(u.z); acc.w += bf2f(u.w);
    }
    *(float4*)&out[off] = acc;
}

// ---------------- bf16 MFMA GEMM, 128x64 tile, BK=64 (grid: M/128, N/64) ----------
// High-occupancy small-N GEMM (512 blocks) — used for the WO projection.
// Single-buffered by design (R9 lesson: dbuf neutral here, inter-block overlap suffices).
template<bool RELU>
__global__ __launch_bounds__(256) void gemm_mfma_64(const ushort_t* __restrict__ A,
                                                    const ushort_t* __restrict__ Bt,
                                                    const float* __restrict__ bias,
                                                    const float* __restrict__ resid,
                                                    float* __restrict__ Cout,
                                                    int M, int N, int K) {
    __shared__ ushort_t As[128 * 64];
    __shared__ ushort_t Bs[64 * 64];

    int tid = threadIdx.x;
    int wave = tid >> 6, lane = tid & 63;
    int m0 = blockIdx.x * 128, n0 = blockIdx.y * 64;
    int l8 = lane >> 3, c8 = lane & 7;
    int cg = c8 ^ l8;

    const ushort_t* gA = A  + (size_t)(m0 + 32 * wave + l8) * K + cg * 8;
    const ushort_t* gB = Bt + (size_t)(n0 + 16 * wave + l8) * K + cg * 8;
    ushort_t* lA = As + (32 * wave) * 64;
    ushort_t* lB = Bs + (16 * wave) * 64;

    f32x4 acc[2][4];
    #pragma unroll
    for (int i = 0; i < 2; i++)
        #pragma unroll
        for (int j = 0; j < 4; j++) acc[i][j] = (f32x4){0.f, 0.f, 0.f, 0.f};

    int wm = 32 * wave;
    int fm = lane & 15;
    int fk = (lane >> 4) * 8;
    int swz = (fm & 7) * 8;

    for (int k0 = 0; k0 < K; k0 += 64) {
        __syncthreads();
        #pragma unroll
        for (int c = 0; c < 4; c++)
            load_lds16(gA + (size_t)(8 * c) * K, lA + (8 * c) * 64);
        #pragma unroll
        for (int c = 0; c < 2; c++)
            load_lds16(gB + (size_t)(8 * c) * K, lB + (8 * c) * 64);
        gA += 64; gB += 64;
        __syncthreads();

        #pragma unroll
        for (int kh = 0; kh < 2; kh++) {
            int kk = kh * 32;
            bf16x8 af[2], bfr[4];
            #pragma unroll
            for (int i = 0; i < 2; i++)
                af[i] = *(const bf16x8*)&As[(wm + 16 * i + fm) * 64 + ((kk + fk) ^ swz)];
            #pragma unroll
            for (int j = 0; j < 4; j++)
                bfr[j] = *(const bf16x8*)&Bs[(16 * j + fm) * 64 + ((kk + fk) ^ swz)];
            #pragma unroll
            for (int i = 0; i < 2; i++)
                #pragma unroll
                for (int j = 0; j < 4; j++)
                    acc[i][j] = __builtin_amdgcn_mfma_f32_16x16x32_bf16(af[i], bfr[j], acc[i][j], 0, 0, 0);
        }
    }

    int col_l = lane & 15, row_l = (lane >> 4) * 4;
    #pragma unroll
    for (int i = 0; i < 2; i++) {
        #pragma unroll
        for (int j = 0; j < 4; j++) {
            int col = n0 + 16 * j + col_l;
            float bia = bias ? bias[col] : 0.f;
            #pragma unroll
            for (int r = 0; r < 4; r++) {
                int row = m0 + wm + 16 * i + row_l + r;
                float c = acc[i][j][r] + bia;
                if (RELU) c = fmaxf(c, 0.f);
                if (resid) c += resid[(size_t)row * N + col];
                Cout[(size_t)row * N + col] = c;
            }
        }
    }
}

// ---------------- MFMA flash attention over COMPACTED keys, S^T form ----------------
// R8/R11 (verified best): QBLK=128, double-buffered K/V staging on the 2-phase
// counted-vmcnt skeleton. Pt rows are wave-private -> no barrier around the pack.
// NOTE (R12/R13 finding): QBLK=64 (4 blocks/CU) makes fattn itself ~17 us faster but
// reproducibly downclocks the subsequent FFN GEMMs by ~0.72x (uniform counter scaling,
// FETCH unchanged) — net zero-to-negative end-to-end. Keep QBLK=128.
__global__ __launch_bounds__(256) void fattn_mfma(const ushort_t* __restrict__ Q,
                                                  const ushort_t* __restrict__ K2,
                                                  const ushort_t* __restrict__ Vt2,
                                                  const int* __restrict__ nunb,
                                                  ushort_t* __restrict__ O) {
    __shared__ ushort_t Ks[2][64 * 64];   // [k][d], chunk-swizzled, double-buffered
    __shared__ ushort_t Vs[2][64 * 64];   // [d][k], chunk-swizzled, double-buffered
    __shared__ ushort_t Pt[128 * 68];     // [q][k], padded (+4); wave-private rows

    int tid = threadIdx.x, wave = tid >> 6, lane = tid & 63;
    int qt = blockIdx.x, h = blockIdx.y, b = blockIdx.z;
    int q0 = qt * 128;
    int l8 = lane >> 3, c8 = lane & 7;
    int cg = c8 ^ l8;

    const int nun = nunb[b];
    const int ntiles = (nun + 63) >> 6;

    const ushort_t* Kg = K2 + ((size_t)(b * SEQ)) * D_MODEL + h * 64;
    const ushort_t* Vg = Vt2 + ((size_t)(b * 1024 + h * 64)) * SEQ;

    int fm = lane & 15, fq = lane >> 4;
    int fk = fq * 8;
    int swz = (fm & 7) * 8;
    const float C2 = 0.18033688f;       // 0.125 * log2(e)

    bf16x8 qf[2][2];
    #pragma unroll
    for (int qg = 0; qg < 2; qg++) {
        int row = q0 + qg * 64 + wave * 16 + fm;
        const ushort_t* qr = Q + (size_t)(b * SEQ + row) * D_MODEL + h * 64;
        qf[qg][0] = *(const bf16x8*)&qr[fk];
        qf[qg][1] = *(const bf16x8*)&qr[32 + fk];
    }

    float l_acc[2] = {0.f, 0.f};
    f32x4 acc_o[2][4];
    #pragma unroll
    for (int qg = 0; qg < 2; qg++)
        #pragma unroll
        for (int j = 0; j < 4; j++) acc_o[qg][j] = (f32x4){0.f, 0.f, 0.f, 0.f};

    // 4 global_load_lds per thread per stage (2 x {K,V})
    #define FATTN_STAGE(KT, BUF)                                                            \
        {                                                                                   \
            int k0s = (KT) * 64;                                                            \
            _Pragma("unroll")                                                               \
            for (int c = 0; c < 2; c++) {                                                   \
                int row = c * 32 + wave * 8 + l8;                                           \
                load_lds16(Kg + (size_t)(k0s + row) * D_MODEL + cg * 8,                     \
                           &Ks[BUF][(c * 32 + wave * 8) * 64]);                             \
                load_lds16(Vg + (size_t)row * SEQ + k0s + cg * 8,                           \
                           &Vs[BUF][(c * 32 + wave * 8) * 64]);                             \
            }                                                                               \
        }

    // prologue: stage tile 0 into buf0 (first iteration's vmcnt covers the wait)
    FATTN_STAGE(0, 0)

    for (int kt = 0; kt < ntiles; kt++) {
        int cur = kt & 1;
        int k0 = kt * 64;
        if (kt + 1 < ntiles) {                      // block-uniform branch
            FATTN_STAGE(kt + 1, cur ^ 1)
            asm volatile("s_waitcnt vmcnt(4)" ::: "memory");   // oldest 4 (tile kt) done
        } else {
            asm volatile("s_waitcnt vmcnt(0)" ::: "memory");
        }
        __builtin_amdgcn_s_barrier();
        asm volatile("" ::: "memory");

        f32x4 sT[2][4];
        #pragma unroll
        for (int qg = 0; qg < 2; qg++)
            #pragma unroll
            for (int jk = 0; jk < 4; jk++) sT[qg][jk] = (f32x4){0.f, 0.f, 0.f, 0.f};
        #pragma unroll
        for (int kh = 0; kh < 2; kh++) {
            bf16x8 kf[4];
            #pragma unroll
            for (int jk = 0; jk < 4; jk++)
                kf[jk] = *(const bf16x8*)&Ks[cur][(16 * jk + fm) * 64 + ((kh * 32 + fk) ^ swz)];
            #pragma unroll
            for (int qg = 0; qg < 2; qg++)
                #pragma unroll
                for (int jk = 0; jk < 4; jk++)
                    sT[qg][jk] = __builtin_amdgcn_mfma_f32_16x16x32_bf16(kf[jk], qf[qg][kh], sT[qg][jk], 0, 0, 0);
        }

        if (k0 + 64 <= nun) {
            #pragma unroll
            for (int qg = 0; qg < 2; qg++)
                #pragma unroll
                for (int jk = 0; jk < 4; jk++) {
                    #pragma unroll
                    for (int r = 0; r < 4; r++) {
                        float p = exp2f(sT[qg][jk][r] * C2);
                        sT[qg][jk][r] = p;
                        l_acc[qg] += p;
                    }
                }
        } else {
            #pragma unroll
            for (int qg = 0; qg < 2; qg++)
                #pragma unroll
                for (int jk = 0; jk < 4; jk++) {
                    int kb = k0 + 16 * jk + 4 * fq;
                    #pragma unroll
                    for (int r = 0; r < 4; r++) {
                        float bias = (kb + r < nun) ? 0.f : -1000.f;
                        float p = exp2f(fmaf(sT[qg][jk][r], C2, bias));
                        sT[qg][jk][r] = p;
                        l_acc[qg] += p;
                    }
                }
        }

        // pack P -> Pt (wave-private rows: written and read only by this wave; no barrier)
        #pragma unroll
        for (int qg = 0; qg < 2; qg++) {
            ushort_t* prow = &Pt[(qg * 64 + wave * 16 + fm) * 68];
            #pragma unroll
            for (int jk = 0; jk < 4; jk++) {
                unsigned u0 = __float_as_uint(sT[qg][jk][0]) + 0x8000u;
                unsigned u1 = __float_as_uint(sT[qg][jk][1]) + 0x8000u;
                unsigned u2 = __float_as_uint(sT[qg][jk][2]) + 0x8000u;
                unsigned u3 = __float_as_uint(sT[qg][jk][3]) + 0x8000u;
                uint2 pk;
                pk.x = __builtin_amdgcn_perm(u1, u0, 0x07060302u);
                pk.y = __builtin_amdgcn_perm(u3, u2, 0x07060302u);
                *(uint2*)&prow[16 * jk + 4 * fq] = pk;
            }
        }

        #pragma unroll
        for (int kh = 0; kh < 2; kh++) {
            bf16x8 vf[4];
            #pragma unroll
            for (int j = 0; j < 4; j++)
                vf[j] = *(const bf16x8*)&Vs[cur][(16 * j + fm) * 64 + ((kh * 32 + fk) ^ swz)];
            #pragma unroll
            for (int qg = 0; qg < 2; qg++) {
                bf16x8 pf = *(const bf16x8*)&Pt[(qg * 64 + wave * 16 + fm) * 68 + kh * 32 + fk];
                #pragma unroll
                for (int j = 0; j < 4; j++)
                    acc_o[qg][j] = __builtin_amdgcn_mfma_f32_16x16x32_bf16(pf, vf[j], acc_o[qg][j], 0, 0, 0);
            }
        }

        // release buf[cur] for overwrite in iteration kt+1 (stage of tile kt+2)
        asm volatile("s_waitcnt lgkmcnt(0)" ::: "memory");
        __builtin_amdgcn_sched_barrier(0);
        __builtin_amdgcn_s_barrier();
        asm volatile("" ::: "memory");
    }
    #undef FATTN_STAGE

    #pragma unroll
    for (int qg = 0; qg < 2; qg++) {
        float l_full = l_acc[qg];
        l_full += __shfl_xor(l_full, 16);
        l_full += __shfl_xor(l_full, 32);
        #pragma unroll
        for (int r = 0; r < 4; r++) {
            float lr = __shfl(l_full, fq * 4 + r);
            float inv = 1.0f / lr;
            int row = q0 + qg * 64 + wave * 16 + fq * 4 + r;
            #pragma unroll
            for (int j = 0; j < 4; j++) {
                int col = h * 64 + 16 * j + fm;
                O[(size_t)(b * SEQ + row) * D_MODEL + col] = f2bf(acc_o[qg][j][r] * inv);
            }
        }
    }
}

// ---------------- launch ----------------
extern "C" void kernel_launch(void* const* d_in, const int* in_sizes, int n_in,
                              void* d_out, int out_size, void* d_ws, size_t ws_size,
                              hipStream_t stream) {
    const float* x    = (const float*)d_in[0];
    const int*   mask = (const int*)  d_in[1];
    const float* wq   = (const float*)d_in[2];
    const float* wk   = (const float*)d_in[3];
    const float* wv   = (const float*)d_in[4];
    const float* wo   = (const float*)d_in[5];
    const float* w1   = (const float*)d_in[6];
    const float* b1   = (const float*)d_in[7];
    const float* w2   = (const float*)d_in[8];
    const float* b2   = (const float*)d_in[9];
    const float* ln1a = (const float*)d_in[10];
    const float* ln1b = (const float*)d_in[11];
    const float* ln2a = (const float*)d_in[12];
    const float* ln2b = (const float*)d_in[13];
    float* out = (float*)d_out;

    char* ws = (char*)d_ws;
    const size_t MB = 1024 * 1024;
    float*    x2    = (float*)   (ws + 0 * MB);    // 16 MB (hosts K2/Vt2 pre-WO)
    ushort_t* K2    = (ushort_t*)(ws + 0 * MB);    // 8 MB  (dead before x2 written)
    ushort_t* Vt2   = (ushort_t*)(ws + 8 * MB);    // 8 MB
    ushort_t* hbf   = (ushort_t*)(ws + 16 * MB);   // 8 MB (LN1/attn/LN2 out)
    ushort_t* qbf   = (ushort_t*)(ws + 24 * MB);   // 8 MB
    ushort_t* ffbf  = (ushort_t*)(ws + 48 * MB);   // 32 MB (FFN1 out)
    ushort_t* wqkvt = (ushort_t*)(ws + 80 * MB);   // 6 MB: wq|wk|wv transposed
    ushort_t* wot   = (ushort_t*)(ws + 86 * MB);   // 2 MB
    ushort_t* w1t   = (ushort_t*)(ws + 88 * MB);   // 8 MB
    ushort_t* w2t   = (ushort_t*)(ws + 96 * MB);   // 8 MB
    int*      idxb  = (int*)     (ws + 104 * MB);
    int*      nunb  = (int*)     (ws + 104 * MB + 64 * 1024);
    ushort_t* pbuf  = (ushort_t*)(ws + 16 * MB);   // 32 MB splitk partials (reuse 16..48,
                                                   //   hbf/qbf dead by FFN2 time)

    ushort_t* wqt = wqkvt;
    ushort_t* wkt = wqkvt + (size_t)1024 * 1024;
    ushort_t* wvt = wqkvt + (size_t)2 * 1024 * 1024;

    dim3 blk(256);
    dim3 blk512(512);

    transpose4_bf16_kernel<<<dim3(16, 16, 4), blk, 0, stream>>>(wq, wk, wv, wo, wqt, wkt, wvt, wot);
    transpose_ffn_kernel<<<dim3(1024, 2), blk, 0, stream>>>(w1, w2, w1t, w2t);
    mask_scan_kernel<<<BATCH, blk, 0, stream>>>(mask, idxb, nunb);

    ln_kernel<<<ROWS, blk, 0, stream>>>(x, ln1a, ln1b, hbf);

    // unified QKV: 128^2 tile, ~528 active blocks; K/V rows gathered in-place via idx
    gemm_qkv<<<dim3(32, 24), blk, 0, stream>>>(hbf, wqkvt, idxb, nunb, qbf, K2, Vt2);

    dim3 g_attn(SEQ / 128, NUM_HEADS, BATCH);
    fattn_mfma<<<g_attn, blk, 0, stream>>>(qbf, K2, Vt2, nunb, hbf);

    // x2 = x + attn @ wo — 128x64 tile, 512 blocks (N=1024 too small for the 256^2 template)
    dim3 g_wo(ROWS / 128, D_MODEL / 64);
    gemm_mfma_64<false><<<g_wo, blk, 0, stream>>>(hbf, wot, nullptr, x, x2, ROWS, D_MODEL, D_MODEL);

    ln_kernel<<<ROWS, blk, 0, stream>>>(x2, ln2a, ln2b, hbf);

    // ff = relu(h2 @ w1 + b1) — verified pipelined 256^2 template (256 blocks = 1/CU)
    dim3 g_ff1(ROWS / 256, D_HIDDEN / 256);
    gemm_mfma_256<true, 1><<<g_ff1, blk512, 0, stream>>>(hbf, w1t, b1, nullptr, ffbf,
                                                         ROWS, D_HIDDEN, D_MODEL);

    // FFN2: pipelined 256x256 split-K=4 + fused reduce (grid 16x4x4 = 256 blocks = 1/CU)
    dim3 g_ff2(ROWS / 256, D_MODEL / 256, 4);
    gemm_splitk_256<<<g_ff2, blk512, 0, stream>>>(ffbf, w2t, pbuf, ROWS, D_MODEL, D_HIDDEN, 4);
    ffn2_reduce<<<ROWS, blk, 0, stream>>>(pbuf, x2, b2, out);
}